// Round 5
// baseline (113.187 us; speedup 1.0000x reference)
//
#include <hip/hip_runtime.h>
#include <hip/hip_bf16.h>

#define NPTS 8192
#define NSL 128          // j-slices (64 points each)
#define HF 96.0f

// Workspace layout (bytes):
//   0        : float  nn2p[128][8192]  partial min d2 (unclamped) per (slice, i)
//   4194304  : int    rkp [128][8192]  partial pz-rank per (slice, i)
//   8388608  : float4 jxyzs[8192]      (x, y, z, x^2+y^2+z^2)
//   8519680  : u64    jkey [8192]      monotone (z, idx) sort key
//   8585216  : float2 pxy[8192]        (px,py) sorted by pz
//   8650752  : float  pzs[8192]
//   8683520  : double sum_part[32]     per-block partial sums of nn_dist
// No init kernel / atomics: every cell written exactly once.

// monotone (z, idx) -> u64 key; strict total order, one u64 compare per pair
__device__ __forceinline__ unsigned long long zkey(float z, int idx) {
    unsigned u = __float_as_uint(z);
    unsigned m = (unsigned)((int)u >> 31) | 0x80000000u;  // neg: FFFFFFFF, pos: 80000000
    return ((unsigned long long)(u ^ m) << 13) | (unsigned)idx;
}

__global__ __launch_bounds__(256) void k_prep(const float* __restrict__ pts,
                                              float4* __restrict__ jxyzs,
                                              unsigned long long* __restrict__ jkey) {
    int i = blockIdx.x * 256 + threadIdx.x;
    float x = pts[3 * i + 0] * HF;
    float y = pts[3 * i + 1] * HF;
    float z = pts[3 * i + 2] * HF;
    jxyzs[i] = make_float4(x, y, z, x * x + y * y + z * z);
    jkey[i] = zkey(z, i);
}

// grid (16 i-blocks of 512, 128 j-slices of 64), block 256 -> 2048 blocks,
// 8 blocks/CU, 100% occupancy, ZERO LDS. The j-point reads are wave-uniform
// (index j0+k, both block-uniform) -> compiler emits s_load into SGPRs; inner
// loop is pure VALU + SMEM (no LDS pipe, no __syncthreads).
// Each thread handles 2 i-points to amortize the broadcast cost.
__global__ __launch_bounds__(256) void k_nn_rank(const float4* __restrict__ jxyzs,
                                                 const unsigned long long* __restrict__ jkey,
                                                 float* __restrict__ nn2p,
                                                 int* __restrict__ rkp) {
    const int tid = threadIdx.x;
    const int bx = blockIdx.x, by = blockIdx.y;
    const int i0 = bx * 512 + tid;
    const int i1 = i0 + 256;
    const int j0 = by * 64;

    const float4 a0 = jxyzs[i0];
    const float4 a1 = jxyzs[i1];
    const unsigned long long k0 = jkey[i0];
    const unsigned long long k1 = jkey[i1];
    const int s0 = i0 - j0;   // self's k (in-range only when this slice covers i0)
    const int s1 = i1 - j0;

    float mn0 = 3.0e38f, mn1 = 3.0e38f;
    int r0 = 0, r1 = 0;
    #pragma unroll 16
    for (int k = 0; k < 64; ++k) {
        const float4 p = jxyzs[j0 + k];               // uniform -> s_load_dwordx4
        const unsigned long long pk = jkey[j0 + k];   // uniform -> s_load_dwordx2
        // reference formula: sq_i + sq_j - 2*dot
        float d20 = a0.w + p.w - 2.0f * (a0.x * p.x + a0.y * p.y + a0.z * p.z);
        float d21 = a1.w + p.w - 2.0f * (a1.x * p.x + a1.y * p.y + a1.z * p.z);
        if (k != s0) mn0 = fminf(mn0, d20);
        if (k != s1) mn1 = fminf(mn1, d21);
        r0 += (int)(pk < k0);   // stable pz rank (index tiebreak via key)
        r1 += (int)(pk < k1);
    }
    nn2p[by * NPTS + i0] = mn0;   // coalesced, written exactly once
    nn2p[by * NPTS + i1] = mn1;
    rkp [by * NPTS + i0] = r0;
    rkp [by * NPTS + i1] = r1;
}

// grid 32, block 256. Reduce partials -> nn_dist + total rank; scatter into
// pz-sorted order; per-block double partial sum of nn_dist.
__global__ __launch_bounds__(256) void k_mid(const float* __restrict__ pts,
                                             const float* __restrict__ nn2p,
                                             const int* __restrict__ rkp,
                                             float2* __restrict__ pxy,
                                             float* __restrict__ pzs,
                                             double* __restrict__ sum_part) {
    const int t = threadIdx.x;
    const int i = blockIdx.x * 256 + t;
    float mn = 3.0e38f;
    int rk = 0;
    #pragma unroll 8
    for (int s = 0; s < NSL; ++s) {
        mn = fminf(mn, nn2p[s * NPTS + i]);   // coalesced across threads
        rk += rkp[s * NPTS + i];
    }
    // clamp commutes with min across slices: min_s max(m_s,0) == max(min_s,0)
    const float nnd = sqrtf(fmaxf(mn, 0.0f));
    pxy[rk] = make_float2(pts[3 * i + 0] * HF, pts[3 * i + 1] * HF);
    pzs[rk] = pts[3 * i + 2] * HF;

    double acc = (double)nnd;
    #pragma unroll
    for (int off = 32; off > 0; off >>= 1) acc += __shfl_down(acc, off, 64);
    __shared__ double sw[4];
    if ((t & 63) == 0) sw[t >> 6] = acc;
    __syncthreads();
    if (t == 0) sum_part[blockIdx.x] = sw[0] + sw[1] + sw[2] + sw[3];
}

// One block per (row, group of 8 cols). Thread t owns point 256k+t of chunk k
// (pz-sorted order) -> coalesced float2 loads. Membership recorded as per-wave
// 64-bit ballots in LDS; rank selection done per-wave in the epilogue.
// delta2 is finalized per-block from the 32 double partials (deterministic:
// same values, same order -> identical result in every block).
// NOTE: replicates reference exactly: px upper bound uses Yr (row-uniform), not Xr.
__global__ __launch_bounds__(256) void k_median(const float2* __restrict__ pxy,
                                                const float* __restrict__ pzs,
                                                const double* __restrict__ sum_part,
                                                float* __restrict__ out) {
    __shared__ unsigned long long bal[8][4][32];  // [cell][wave][chunk]
    __shared__ float s_dd;
    const int t = threadIdx.x;
    const int lane = t & 63;
    const int w = t >> 6;
    const int row = blockIdx.y;      // 96
    const int cg = blockIdx.x;       // 12 col-groups of 8
    if (t == 0) {
        double s = 0.0;
        #pragma unroll
        for (int b = 0; b < 32; ++b) s += sum_part[b];
        float mean = (float)(s / (double)NPTS);
        float avg = 3.0f * mean;     // M_FACTOR * mean
        s_dd = 3.0f * avg;           // M_FACTOR * avg
    }
    __syncthreads();
    const float d = s_dd;
    const float Yf = (float)(row - 48);
    const float ylo = Yf - d, yhi = Yf + d, xhi = Yf + d;
    float xlo[8];
    #pragma unroll
    for (int c = 0; c < 8; ++c) xlo[c] = (float)(cg * 8 + c - 48) - d;

    #pragma unroll 4
    for (int k = 0; k < 32; ++k) {
        float2 p = pxy[(k << 8) + t];
        bool pre = (p.y >= ylo) && (p.y <= yhi) && (p.x <= xhi);
        unsigned long long b[8];
        #pragma unroll
        for (int c = 0; c < 8; ++c) b[c] = __ballot(pre && (p.x >= xlo[c]));
        if (lane == 0) {
            #pragma unroll
            for (int c = 0; c < 8; ++c) bal[c][w][k] = b[c];
        }
    }
    __syncthreads();

    // wave w handles cells 2w and 2w+1; lanes 0..31 each own one chunk
    #pragma unroll
    for (int c2 = 0; c2 < 2; ++c2) {
        const int c = w * 2 + c2;
        const int l = (lane < 32) ? lane : 31;
        const unsigned long long bw0 = bal[c][0][l];
        const unsigned long long bw1 = bal[c][1][l];
        const unsigned long long bw2 = bal[c][2][l];
        const unsigned long long bw3 = bal[c][3][l];
        const int cnt = __popcll(bw0) + __popcll(bw1) + __popcll(bw2) + __popcll(bw3);
        const int cl = (lane < 32) ? cnt : 0;
        int incl = cl;
        #pragma unroll
        for (int off = 1; off < 64; off <<= 1) {
            int v = __shfl_up(incl, off, 64);
            if (lane >= off) incl += v;
        }
        const int ct = __shfl(incl, 63, 64);  // total count c
        const int og = row * 96 + cg * 8 + c;
        if (ct == 0) {
            if (lane == 0) out[og] = 0.0f;
            continue;
        }
        const int excl = incl - cl;
        float vv[2];
        #pragma unroll
        for (int sel = 0; sel < 2; ++sel) {
            const int target = sel ? (ct >> 1) : ((ct - 1) >> 1);
            const bool pred = (lane < 32) && (target >= excl) && (target < excl + cl);
            unsigned long long bm = __ballot(pred);
            int src = __ffsll(bm) - 1;  // exactly one lane holds the target
            float val = 0.0f;
            if (pred) {
                int r = target - excl;
                int pc0 = __popcll(bw0), pc1 = __popcll(bw1), pc2 = __popcll(bw2);
                unsigned long long x;
                int base;
                if (r < pc0)              { x = bw0; base = 0; }
                else if (r < pc0 + pc1)   { x = bw1; base = 64;  r -= pc0; }
                else if (r < pc0+pc1+pc2) { x = bw2; base = 128; r -= pc0 + pc1; }
                else                      { x = bw3; base = 192; r -= pc0 + pc1 + pc2; }
                for (int q = 0; q < r; ++q) x &= x - 1;  // drop r lowest set bits
                val = pzs[(lane << 8) + base + (__ffsll(x) - 1)];
            }
            vv[sel] = __shfl(val, src, 64);
        }
        if (lane == 0) {
            float med = 0.5f * (vv[0] + vv[1]);
            out[og] = (med + 48.0f) * (1.0f / 96.0f);
        }
    }
}

extern "C" void kernel_launch(void* const* d_in, const int* in_sizes, int n_in,
                              void* d_out, int out_size, void* d_ws, size_t ws_size,
                              hipStream_t stream) {
    const float* pts = (const float*)d_in[0];
    float* out = (float*)d_out;

    char* ws = (char*)d_ws;
    float* nn2p              = (float*)(ws + 0);
    int* rkp                 = (int*)(ws + 4194304);
    float4* jxyzs            = (float4*)(ws + 8388608);
    unsigned long long* jkey = (unsigned long long*)(ws + 8519680);
    float2* pxy              = (float2*)(ws + 8585216);
    float* pzs               = (float*)(ws + 8650752);
    double* sum_part         = (double*)(ws + 8683520);

    k_prep<<<NPTS / 256, 256, 0, stream>>>(pts, jxyzs, jkey);
    k_nn_rank<<<dim3(16, NSL), 256, 0, stream>>>(jxyzs, jkey, nn2p, rkp);
    k_mid<<<32, 256, 0, stream>>>(pts, nn2p, rkp, pxy, pzs, sum_part);
    k_median<<<dim3(12, 96), 256, 0, stream>>>(pxy, pzs, sum_part, out);
}

// Round 6
// 108.310 us; speedup vs baseline: 1.0450x; 1.0450x over previous
//
#include <hip/hip_runtime.h>
#include <hip/hip_bf16.h>

#define NPTS 8192
#define NSL 64          // j-slices (128 points each)
#define HF 96.0f

// Workspace layout (bytes):
//   0        : float  nn2p[64][8192]   partial min d2 (unclamped) per (slice, i)
//   2097152  : int    rkp [64][8192]   partial pz-rank per (slice, i)
//   4194304  : float2 pxy[8192]        (px,py) sorted by pz
//   4259840  : float  pzs[8192]
//   4292608  : double sum_part[32]     per-block partial sums of nn_dist
// No init kernel / atomics: every cell written exactly once.

// monotone (z, idx) -> u64 key; strict total order, one u64 compare per pair
__device__ __forceinline__ unsigned long long zkey(float z, int idx) {
    unsigned u = __float_as_uint(z);
    unsigned m = (unsigned)((int)u >> 31) | 0x80000000u;  // neg: FFFFFFFF, pos: 80000000
    return ((unsigned long long)(u ^ m) << 13) | (unsigned)idx;
}

// grid (8 i-blocks of 1024, 64 j-slices of 128), block 256 -> 512 blocks.
// FOUR i-points per thread: one ds_read_b128 + ds_read_b64 feeds 256 pairs per
// wave-iter (LDS ~20cyc << VALU ~56cyc) -> VALU-bound, ~4x less LDS pressure
// than the 1-i-point version (which was LDS-pipe-bound at ~34us).
__global__ __launch_bounds__(256) void k_nn_rank(const float* __restrict__ pts,
                                                 float* __restrict__ nn2p,
                                                 int* __restrict__ rkp) {
    __shared__ float4 sj[128];               // (-2x, -2y, -2z, sq)
    __shared__ unsigned long long kj[128];   // z-order key
    const int tid = threadIdx.x;
    const int bx = blockIdx.x, by = blockIdx.y;
    const int j0 = by * 128;
    if (tid < 128) {
        int j = j0 + tid;
        float x = pts[3 * j + 0] * HF;
        float y = pts[3 * j + 1] * HF;
        float z = pts[3 * j + 2] * HF;
        sj[tid] = make_float4(-2.0f * x, -2.0f * y, -2.0f * z,
                              x * x + y * y + z * z);
        kj[tid] = zkey(z, j);
    }
    float xi[4], yi[4], zi[4], sqi[4];
    unsigned long long ki[4];
    int iq[4];
    #pragma unroll
    for (int q = 0; q < 4; ++q) {
        int i = bx * 1024 + q * 256 + tid;
        iq[q] = i;
        float x = pts[3 * i + 0] * HF;
        float y = pts[3 * i + 1] * HF;
        float z = pts[3 * i + 2] * HF;
        xi[q] = x; yi[q] = y; zi[q] = z;
        sqi[q] = x * x + y * y + z * z;
        ki[q] = zkey(z, i);
    }
    __syncthreads();

    float mn[4] = {3.0e38f, 3.0e38f, 3.0e38f, 3.0e38f};
    int rk[4] = {0, 0, 0, 0};
    // this j-slice can contain a self-pair iff by in [8*bx, 8*bx+8): block-uniform
    if ((by >> 3) != bx) {
        #pragma unroll 8
        for (int k = 0; k < 128; ++k) {
            const float4 p = sj[k];
            const unsigned long long pk = kj[k];
            #pragma unroll
            for (int q = 0; q < 4; ++q) {
                // reference formula: sq_i + sq_j - 2*dot
                float d2 = fmaf(p.x, xi[q], fmaf(p.y, yi[q],
                            fmaf(p.z, zi[q], sqi[q] + p.w)));
                mn[q] = fminf(mn[q], d2);
                rk[q] += (int)(pk < ki[q]);   // stable pz rank (key tiebreak)
            }
        }
    } else {
        int sq_[4];
        #pragma unroll
        for (int q = 0; q < 4; ++q) sq_[q] = iq[q] - j0;  // self k (may be OOR)
        #pragma unroll 8
        for (int k = 0; k < 128; ++k) {
            const float4 p = sj[k];
            const unsigned long long pk = kj[k];
            #pragma unroll
            for (int q = 0; q < 4; ++q) {
                float d2 = fmaf(p.x, xi[q], fmaf(p.y, yi[q],
                            fmaf(p.z, zi[q], sqi[q] + p.w)));
                if (k != sq_[q]) mn[q] = fminf(mn[q], d2);
                rk[q] += (int)(pk < ki[q]);
            }
        }
    }
    #pragma unroll
    for (int q = 0; q < 4; ++q) {
        nn2p[by * NPTS + iq[q]] = mn[q];   // coalesced, written exactly once
        rkp [by * NPTS + iq[q]] = rk[q];
    }
}

// grid 32, block 256. Reduce partials -> nn_dist + total rank; scatter into
// pz-sorted order; per-block double partial sum of nn_dist.
__global__ __launch_bounds__(256) void k_mid(const float* __restrict__ pts,
                                             const float* __restrict__ nn2p,
                                             const int* __restrict__ rkp,
                                             float2* __restrict__ pxy,
                                             float* __restrict__ pzs,
                                             double* __restrict__ sum_part) {
    const int t = threadIdx.x;
    const int i = blockIdx.x * 256 + t;
    float mn = 3.0e38f;
    int rk = 0;
    #pragma unroll 8
    for (int s = 0; s < NSL; ++s) {
        mn = fminf(mn, nn2p[s * NPTS + i]);   // coalesced across threads
        rk += rkp[s * NPTS + i];
    }
    // clamp commutes with min across slices: min_s max(m_s,0) == max(min_s,0)
    const float nnd = sqrtf(fmaxf(mn, 0.0f));
    pxy[rk] = make_float2(pts[3 * i + 0] * HF, pts[3 * i + 1] * HF);
    pzs[rk] = pts[3 * i + 2] * HF;

    double acc = (double)nnd;
    #pragma unroll
    for (int off = 32; off > 0; off >>= 1) acc += __shfl_down(acc, off, 64);
    __shared__ double sw[4];
    if ((t & 63) == 0) sw[t >> 6] = acc;
    __syncthreads();
    if (t == 0) sum_part[blockIdx.x] = sw[0] + sw[1] + sw[2] + sw[3];
}

// One block per (row, group of 8 cols). Thread t owns point 256k+t of chunk k
// (pz-sorted order) -> coalesced float2 loads. Membership recorded as per-wave
// 64-bit ballots in LDS; rank selection done per-wave in the epilogue.
// delta2 is finalized per-block from the 32 double partials (deterministic:
// same values, same order -> identical result in every block).
// NOTE: replicates reference exactly: px upper bound uses Yr (row-uniform), not Xr.
__global__ __launch_bounds__(256) void k_median(const float2* __restrict__ pxy,
                                                const float* __restrict__ pzs,
                                                const double* __restrict__ sum_part,
                                                float* __restrict__ out) {
    __shared__ unsigned long long bal[8][4][32];  // [cell][wave][chunk]
    __shared__ float s_dd;
    const int t = threadIdx.x;
    const int lane = t & 63;
    const int w = t >> 6;
    const int row = blockIdx.y;      // 96
    const int cg = blockIdx.x;       // 12 col-groups of 8
    if (t == 0) {
        double s = 0.0;
        #pragma unroll
        for (int b = 0; b < 32; ++b) s += sum_part[b];
        float mean = (float)(s / (double)NPTS);
        float avg = 3.0f * mean;     // M_FACTOR * mean
        s_dd = 3.0f * avg;           // M_FACTOR * avg
    }
    __syncthreads();
    const float d = s_dd;
    const float Yf = (float)(row - 48);
    const float ylo = Yf - d, yhi = Yf + d, xhi = Yf + d;
    float xlo[8];
    #pragma unroll
    for (int c = 0; c < 8; ++c) xlo[c] = (float)(cg * 8 + c - 48) - d;

    #pragma unroll 4
    for (int k = 0; k < 32; ++k) {
        float2 p = pxy[(k << 8) + t];
        bool pre = (p.y >= ylo) && (p.y <= yhi) && (p.x <= xhi);
        unsigned long long b[8];
        #pragma unroll
        for (int c = 0; c < 8; ++c) b[c] = __ballot(pre && (p.x >= xlo[c]));
        if (lane == 0) {
            #pragma unroll
            for (int c = 0; c < 8; ++c) bal[c][w][k] = b[c];
        }
    }
    __syncthreads();

    // wave w handles cells 2w and 2w+1; lanes 0..31 each own one chunk
    #pragma unroll
    for (int c2 = 0; c2 < 2; ++c2) {
        const int c = w * 2 + c2;
        const int l = (lane < 32) ? lane : 31;
        const unsigned long long bw0 = bal[c][0][l];
        const unsigned long long bw1 = bal[c][1][l];
        const unsigned long long bw2 = bal[c][2][l];
        const unsigned long long bw3 = bal[c][3][l];
        const int cnt = __popcll(bw0) + __popcll(bw1) + __popcll(bw2) + __popcll(bw3);
        const int cl = (lane < 32) ? cnt : 0;
        int incl = cl;
        #pragma unroll
        for (int off = 1; off < 64; off <<= 1) {
            int v = __shfl_up(incl, off, 64);
            if (lane >= off) incl += v;
        }
        const int ct = __shfl(incl, 63, 64);  // total count c
        const int og = row * 96 + cg * 8 + c;
        if (ct == 0) {
            if (lane == 0) out[og] = 0.0f;
            continue;
        }
        const int excl = incl - cl;
        float vv[2];
        #pragma unroll
        for (int sel = 0; sel < 2; ++sel) {
            const int target = sel ? (ct >> 1) : ((ct - 1) >> 1);
            const bool pred = (lane < 32) && (target >= excl) && (target < excl + cl);
            unsigned long long bm = __ballot(pred);
            int src = __ffsll(bm) - 1;  // exactly one lane holds the target
            float val = 0.0f;
            if (pred) {
                int r = target - excl;
                int pc0 = __popcll(bw0), pc1 = __popcll(bw1), pc2 = __popcll(bw2);
                unsigned long long x;
                int base;
                if (r < pc0)              { x = bw0; base = 0; }
                else if (r < pc0 + pc1)   { x = bw1; base = 64;  r -= pc0; }
                else if (r < pc0+pc1+pc2) { x = bw2; base = 128; r -= pc0 + pc1; }
                else                      { x = bw3; base = 192; r -= pc0 + pc1 + pc2; }
                for (int q = 0; q < r; ++q) x &= x - 1;  // drop r lowest set bits
                val = pzs[(lane << 8) + base + (__ffsll(x) - 1)];
            }
            vv[sel] = __shfl(val, src, 64);
        }
        if (lane == 0) {
            float med = 0.5f * (vv[0] + vv[1]);
            out[og] = (med + 48.0f) * (1.0f / 96.0f);
        }
    }
}

extern "C" void kernel_launch(void* const* d_in, const int* in_sizes, int n_in,
                              void* d_out, int out_size, void* d_ws, size_t ws_size,
                              hipStream_t stream) {
    const float* pts = (const float*)d_in[0];
    float* out = (float*)d_out;

    char* ws = (char*)d_ws;
    float* nn2p      = (float*)(ws + 0);
    int* rkp         = (int*)(ws + 2097152);
    float2* pxy      = (float2*)(ws + 4194304);
    float* pzs       = (float*)(ws + 4259840);
    double* sum_part = (double*)(ws + 4292608);

    k_nn_rank<<<dim3(8, NSL), 256, 0, stream>>>(pts, nn2p, rkp);
    k_mid<<<32, 256, 0, stream>>>(pts, nn2p, rkp, pxy, pzs, sum_part);
    k_median<<<dim3(12, 96), 256, 0, stream>>>(pxy, pzs, sum_part, out);
}